// Round 1
// baseline (418.180 us; speedup 1.0000x reference)
//
#include <hip/hip_runtime.h>

// SSIM, fused single-pass: 7x7 uniform box filter via separable sliding
// windows, per-block partial sums, double accumulator in d_ws, finalize
// kernel writes the scalar mean.
//
// Geometry: inputs 16 x 1 x 1080 x 1920 fp32; VALID 7x7 -> 16 x 1074 x 1914.

constexpr int W_IN = 1920;
constexpr int H_IN = 1080;
constexpr int WOUT = W_IN - 6;   // 1914
constexpr int HOUT = H_IN - 6;   // 1074
constexpr int NBATCH = 16;

constexpr int TW = 256;          // output columns per block (1 per thread)
constexpr int TH = 64;           // output rows per block
constexpr int SROWS = 7;         // input rows staged per stage
constexpr int NSTAGES = (TH + 6) / SROWS;  // 10 stages = 70 input rows
constexpr int LSTRIDE = 264;     // LDS floats per row (262 used; 16B-aligned rows)
constexpr int C4_PER_ROW = 66;   // float4 loads per row (264 floats, clamped)
constexpr int TASKS_PER_IMG = SROWS * C4_PER_ROW;  // 462
constexpr int TASKS = 2 * TASKS_PER_IMG;           // 924

constexpr float C1f = 6.5025f;     // (0.01*255)^2
constexpr float C2f = 58.5225f;    // (0.03*255)^2
constexpr float INV49 = 1.0f / 49.0f;

__global__ __launch_bounds__(256)
void ssim_kernel(const float* __restrict__ img1, const float* __restrict__ img2,
                 double* __restrict__ acc) {
  const int tid = threadIdx.x;
  const int x0 = blockIdx.x * TW;
  const int y0 = blockIdx.y * TH;
  const size_t ibase = (size_t)blockIdx.z * (size_t)(H_IN * W_IN);
  const float* __restrict__ b1p = img1 + ibase;
  const float* __restrict__ b2p = img2 + ibase;

  // double-buffered stage: [buf][img][row][col]; 2*2*7*264*4 = 29.5 KB
  __shared__ float sbuf[2][2][SROWS][LSTRIDE];
  __shared__ float warpsum[4];

  float4 lreg[4];

  auto stage_gload = [&](int row0) {
#pragma unroll
    for (int k = 0; k < 4; ++k) {
      const int i = tid + k * 256;
      if (i < TASKS) {
        const int im = (i >= TASKS_PER_IMG) ? 1 : 0;
        const int rem = i - im * TASKS_PER_IMG;
        const int r = rem / C4_PER_ROW;
        const int c = rem - r * C4_PER_ROW;
        const int gy = min(y0 + row0 + r, H_IN - 1);
        // clamp keeps the float4 in-bounds; clamped (junk) columns only feed
        // LDS cols >= 128 of the last x-tile, which no valid output reads.
        const int gx = min(x0 + c * 4, W_IN - 4);
        const float* p = (im ? b2p : b1p) + (size_t)gy * W_IN + gx;
        lreg[k] = *reinterpret_cast<const float4*>(p);
      }
    }
  };
  auto stage_swrite = [&](int buf) {
#pragma unroll
    for (int k = 0; k < 4; ++k) {
      const int i = tid + k * 256;
      if (i < TASKS) {
        const int im = (i >= TASKS_PER_IMG) ? 1 : 0;
        const int rem = i - im * TASKS_PER_IMG;
        const int r = rem / C4_PER_ROW;
        const int c = rem - r * C4_PER_ROW;
        *reinterpret_cast<float4*>(&sbuf[buf][im][r][c * 4]) = lreg[k];
      }
    }
  };

  // vertical sliding window of horizontal rowsums (5 quantities x 7 rows)
  float w1[7], w2[7], w11[7], w22[7], w12[7];
#pragma unroll
  for (int k = 0; k < 7; ++k) {
    w1[k] = 0.f; w2[k] = 0.f; w11[k] = 0.f; w22[k] = 0.f; w12[k] = 0.f;
  }

  float accv = 0.0f;
  const bool colv = (x0 + tid) < WOUT;

  // prologue: stage 0 -> buffer 0
  stage_gload(0);
  stage_swrite(0);

  for (int s = 0; s < NSTAGES; ++s) {
    if (s + 1 < NSTAGES) stage_gload((s + 1) * SROWS);
    __syncthreads();  // buf[s&1] writes visible; prior reads of buf[(s+1)&1] done
    if (s + 1 < NSTAGES) stage_swrite((s + 1) & 1);
    const int cb = s & 1;
#pragma unroll
    for (int j = 0; j < SROWS; ++j) {
      const float* r1 = &sbuf[cb][0][j][tid];
      const float* r2 = &sbuf[cb][1][j][tid];
      float t1 = 0.f, t2 = 0.f, t11 = 0.f, t22 = 0.f, t12 = 0.f;
#pragma unroll
      for (int d = 0; d < 7; ++d) {
        const float a = r1[d];
        const float b = r2[d];
        t1 += a;
        t2 += b;
        t11 = fmaf(a, a, t11);
        t22 = fmaf(b, b, t22);
        t12 = fmaf(a, b, t12);
      }
      // shift window, insert new rowsums
#pragma unroll
      for (int k = 0; k < 6; ++k) {
        w1[k] = w1[k + 1]; w2[k] = w2[k + 1]; w11[k] = w11[k + 1];
        w22[k] = w22[k + 1]; w12[k] = w12[k + 1];
      }
      w1[6] = t1; w2[6] = t2; w11[6] = t11; w22[6] = t22; w12[6] = t12;

      const int ridx = s * SROWS + j;  // input row index relative to y0
      if (ridx >= 6) {
        const float bs1  = ((w1[0]+w1[1])+(w1[2]+w1[3]))+((w1[4]+w1[5])+w1[6]);
        const float bs2  = ((w2[0]+w2[1])+(w2[2]+w2[3]))+((w2[4]+w2[5])+w2[6]);
        const float bs11 = ((w11[0]+w11[1])+(w11[2]+w11[3]))+((w11[4]+w11[5])+w11[6]);
        const float bs22 = ((w22[0]+w22[1])+(w22[2]+w22[3]))+((w22[4]+w22[5])+w22[6]);
        const float bs12 = ((w12[0]+w12[1])+(w12[2]+w12[3]))+((w12[4]+w12[5])+w12[6]);
        const float mu1 = bs1 * INV49, mu2 = bs2 * INV49;
        const float mu1s = mu1 * mu1, mu2s = mu2 * mu2, mu12 = mu1 * mu2;
        const float sg1  = bs11 * INV49 - mu1s;
        const float sg2  = bs22 * INV49 - mu2s;
        const float sg12 = bs12 * INV49 - mu12;
        const float v1 = 2.0f * sg12 + C2f;
        const float v2 = sg1 + sg2 + C2f;
        const float num = (2.0f * mu12 + C1f) * v1;
        const float den = (mu1s + mu2s + C1f) * v2;
        const float ssim = num / den;
        const int oy = y0 + ridx - 6;
        if (colv && oy < HOUT) accv += ssim;
      }
    }
  }

  // block reduction: wave shuffle (64-wide) -> LDS -> one double atomic
#pragma unroll
  for (int off = 32; off > 0; off >>= 1) accv += __shfl_down(accv, off);
  if ((tid & 63) == 0) warpsum[tid >> 6] = accv;
  __syncthreads();
  if (tid == 0) {
    const double s = (double)warpsum[0] + (double)warpsum[1] +
                     (double)warpsum[2] + (double)warpsum[3];
    atomicAdd(acc, s);
  }
}

__global__ void finalize_kernel(const double* __restrict__ acc,
                                float* __restrict__ out) {
  out[0] = (float)(acc[0] * (1.0 / ((double)NBATCH * (double)HOUT * (double)WOUT)));
}

extern "C" void kernel_launch(void* const* d_in, const int* in_sizes, int n_in,
                              void* d_out, int out_size, void* d_ws, size_t ws_size,
                              hipStream_t stream) {
  const float* img1 = (const float*)d_in[0];
  const float* img2 = (const float*)d_in[1];
  // d_in[2] is the uniform 1/49 window — baked into INV49.
  double* acc = (double*)d_ws;
  hipMemsetAsync(d_ws, 0, sizeof(double), stream);  // ws is poisoned 0xAA
  dim3 grid((WOUT + TW - 1) / TW, (HOUT + TH - 1) / TH, NBATCH);  // 8 x 17 x 16
  hipLaunchKernelGGL(ssim_kernel, grid, dim3(256), 0, stream, img1, img2, acc);
  hipLaunchKernelGGL(finalize_kernel, dim3(1), dim3(1), 0, stream, acc,
                     (float*)d_out);
}

// Round 2
// 300.674 us; speedup vs baseline: 1.3908x; 1.3908x over previous
//
#include <hip/hip_runtime.h>

// SSIM fused single-pass, round 2: all per-thread state in NAMED SCALARS
// (round 1's lambda-captured arrays spilled to scratch: 181 MB WRITE_SIZE).
// Vertical 7-window is a static ring (stage height == 7) -> no shift moves.
// Per-block partials in d_ws (no atomic, no memset dispatch).
//
// Geometry: 16 x 1 x 1080 x 1920 fp32; VALID 7x7 -> 16 x 1074 x 1914.

constexpr int W_IN = 1920;
constexpr int H_IN = 1080;
constexpr int WOUT = W_IN - 6;   // 1914
constexpr int HOUT = H_IN - 6;   // 1074
constexpr int NBATCH = 16;

constexpr int TW = 256;          // output columns per block (1 per thread)
constexpr int TH = 64;           // output rows per block
constexpr int SROWS = 7;         // input rows per stage
constexpr int NSTAGES = 10;      // 70 input rows -> 64 output rows
constexpr int LSTRIDE = 264;     // LDS floats per staged row
constexpr int C4_PER_ROW = 66;   // float4 loads per row
constexpr int TASKS_PER_IMG = SROWS * C4_PER_ROW;  // 462
constexpr int TASKS = 2 * TASKS_PER_IMG;           // 924
constexpr int IMG_OFF = SROWS * LSTRIDE;           // 1848 floats
constexpr int BUF_OFF = 2 * IMG_OFF;               // 3696 floats

constexpr int NBX = 8, NBY = 17;
constexpr int NBLOCKS = NBX * NBY * NBATCH;        // 2176

constexpr float C1f = 6.5025f;
constexpr float C2f = 58.5225f;
constexpr float INV49 = 1.0f / 49.0f;

__global__ __launch_bounds__(256)
void ssim_kernel(const float* __restrict__ img1, const float* __restrict__ img2,
                 double* __restrict__ partial) {
  const int tid = threadIdx.x;
  const int x0 = blockIdx.x * TW;
  const int y0 = blockIdx.y * TH;
  const size_t ibase = (size_t)blockIdx.z * (size_t)(H_IN * W_IN);
  const float* __restrict__ b1p = img1 + ibase;
  const float* __restrict__ b2p = img2 + ibase;

  __shared__ float sh[2 * BUF_OFF];   // 29568 B
  __shared__ float warpsum[4];

  // ---- staging decode: invariant across stages, all named scalars ----
#define DECODE(K)                                                        \
  const int  i##K  = tid + (K)*256;                                      \
  const bool v##K  = i##K < TASKS;                                       \
  const int  im##K = (i##K >= TASKS_PER_IMG) ? 1 : 0;                    \
  const int  rm##K = i##K - im##K * TASKS_PER_IMG;                       \
  const int  r##K  = rm##K / C4_PER_ROW;                                 \
  const int  c##K  = rm##K - r##K * C4_PER_ROW;                          \
  const int  gx##K = min(x0 + c##K * 4, W_IN - 4);                       \
  const float* pb##K = (im##K ? b2p : b1p) + gx##K;                      \
  const int  ld##K = (im##K * SROWS + r##K) * LSTRIDE + c##K * 4;
  DECODE(0) DECODE(1) DECODE(2) DECODE(3)
#undef DECODE

  float4 g0, g1, g2, g3;
#define GLOAD(K, ROW0)                                                   \
  if (v##K) {                                                            \
    const int gy = min(y0 + (ROW0) + r##K, H_IN - 1);                    \
    g##K = *reinterpret_cast<const float4*>(pb##K + (size_t)gy * W_IN);  \
  }
#define SWRITE(K, BUFBASE)                                               \
  if (v##K) *reinterpret_cast<float4*>(sh + (BUFBASE) + ld##K) = g##K;

  // ---- vertical ring buffer: 5 quantities x 7 slots, named scalars ----
#define DECL_SLOT(J) float h1_##J, h2_##J, h11_##J, h22_##J, h12_##J;
  DECL_SLOT(0) DECL_SLOT(1) DECL_SLOT(2) DECL_SLOT(3)
  DECL_SLOT(4) DECL_SLOT(5) DECL_SLOT(6)
#undef DECL_SLOT

  float accv = 0.0f;
  const bool colv = (x0 + tid) < WOUT;

  // prologue: stage 0 -> buffer 0
  GLOAD(0, 0) GLOAD(1, 0) GLOAD(2, 0) GLOAD(3, 0)
  SWRITE(0, 0) SWRITE(1, 0) SWRITE(2, 0) SWRITE(3, 0)

  for (int s = 0; s < NSTAGES; ++s) {
    const int nrow0 = (s + 1) * SROWS;
    if (s + 1 < NSTAGES) {
      GLOAD(0, nrow0) GLOAD(1, nrow0) GLOAD(2, nrow0) GLOAD(3, nrow0)
    }
    __syncthreads();
    if (s + 1 < NSTAGES) {
      const int nb = ((s + 1) & 1) * BUF_OFF;
      SWRITE(0, nb) SWRITE(1, nb) SWRITE(2, nb) SWRITE(3, nb)
    }
    const float* rowbase = sh + (s & 1) * BUF_OFF + tid;

    // one row-step: horizontal 7-tap into ring slot J; vertical sum of all
    // 7 slots (order-independent) once the window is full.
#define ROWSTEP(J)                                                           \
  {                                                                          \
    const float* ra = rowbase + (J) * LSTRIDE;                               \
    const float* rb = ra + IMG_OFF;                                          \
    float t1 = 0.f, t2 = 0.f, t11 = 0.f, t22 = 0.f, t12 = 0.f;               \
    _Pragma("unroll")                                                        \
    for (int d = 0; d < 7; ++d) {                                            \
      const float a = ra[d];                                                 \
      const float b = rb[d];                                                 \
      t1 += a; t2 += b;                                                      \
      t11 = fmaf(a, a, t11); t22 = fmaf(b, b, t22); t12 = fmaf(a, b, t12);   \
    }                                                                        \
    h1_##J = t1; h2_##J = t2; h11_##J = t11; h22_##J = t22; h12_##J = t12;   \
    const int ridx = s * SROWS + (J);                                        \
    if (ridx >= 6) {                                                         \
      const float bs1  = ((h1_0+h1_1)+(h1_2+h1_3))+((h1_4+h1_5)+h1_6);       \
      const float bs2  = ((h2_0+h2_1)+(h2_2+h2_3))+((h2_4+h2_5)+h2_6);       \
      const float bs11 = ((h11_0+h11_1)+(h11_2+h11_3))+((h11_4+h11_5)+h11_6);\
      const float bs22 = ((h22_0+h22_1)+(h22_2+h22_3))+((h22_4+h22_5)+h22_6);\
      const float bs12 = ((h12_0+h12_1)+(h12_2+h12_3))+((h12_4+h12_5)+h12_6);\
      const float mu1 = bs1 * INV49, mu2 = bs2 * INV49;                      \
      const float mu1s = mu1 * mu1, mu2s = mu2 * mu2, mu12 = mu1 * mu2;      \
      const float sg1  = fmaf(bs11, INV49, -mu1s);                           \
      const float sg2  = fmaf(bs22, INV49, -mu2s);                           \
      const float sg12 = fmaf(bs12, INV49, -mu12);                           \
      const float v1 = 2.0f * sg12 + C2f;                                    \
      const float v2 = sg1 + sg2 + C2f;                                      \
      const float num = (2.0f * mu12 + C1f) * v1;                            \
      const float den = (mu1s + mu2s + C1f) * v2;                            \
      const float ssim = num * __builtin_amdgcn_rcpf(den);                   \
      const int oy = y0 + ridx - 6;                                          \
      if (colv && oy < HOUT) accv += ssim;                                   \
    }                                                                        \
  }
    ROWSTEP(0) ROWSTEP(1) ROWSTEP(2) ROWSTEP(3)
    ROWSTEP(4) ROWSTEP(5) ROWSTEP(6)
#undef ROWSTEP
  }

  // block reduction: 64-wide shuffle -> LDS -> one double per block
#pragma unroll
  for (int off = 32; off > 0; off >>= 1) accv += __shfl_down(accv, off);
  if ((tid & 63) == 0) warpsum[tid >> 6] = accv;
  __syncthreads();
  if (tid == 0) {
    const double s = (double)warpsum[0] + (double)warpsum[1] +
                     (double)warpsum[2] + (double)warpsum[3];
    const int bid = blockIdx.x + NBX * (blockIdx.y + NBY * blockIdx.z);
    partial[bid] = s;
  }
}

__global__ __launch_bounds__(256)
void finalize_kernel(const double* __restrict__ partial,
                     float* __restrict__ out) {
  const int tid = threadIdx.x;
  double s = 0.0;
  for (int i = tid; i < NBLOCKS; i += 256) s += partial[i];
#pragma unroll
  for (int off = 32; off > 0; off >>= 1) s += __shfl_down(s, off);
  __shared__ double ws[4];
  if ((tid & 63) == 0) ws[tid >> 6] = s;
  __syncthreads();
  if (tid == 0) {
    const double tot = ws[0] + ws[1] + ws[2] + ws[3];
    out[0] = (float)(tot / ((double)NBATCH * (double)HOUT * (double)WOUT));
  }
}

extern "C" void kernel_launch(void* const* d_in, const int* in_sizes, int n_in,
                              void* d_out, int out_size, void* d_ws, size_t ws_size,
                              hipStream_t stream) {
  const float* img1 = (const float*)d_in[0];
  const float* img2 = (const float*)d_in[1];
  // d_in[2] is the uniform 1/49 window -- baked into INV49.
  double* partial = (double*)d_ws;  // NBLOCKS doubles, every slot written
  dim3 grid(NBX, NBY, NBATCH);      // 8 x 17 x 16 = 2176 blocks
  hipLaunchKernelGGL(ssim_kernel, grid, dim3(256), 0, stream, img1, img2,
                     partial);
  hipLaunchKernelGGL(finalize_kernel, dim3(1), dim3(256), 0, stream, partial,
                     (float*)d_out);
}